// Round 5
// baseline (430.814 us; speedup 1.0000x reference)
//
#include <hip/hip_runtime.h>
#include <hip/hip_bf16.h>

typedef unsigned short u16;
typedef __attribute__((ext_vector_type(4))) unsigned short u16x4;
typedef __attribute__((ext_vector_type(8))) unsigned short u16x8;
typedef __attribute__((ext_vector_type(8))) short bf16x8;   // 8 bf16 = 4 VGPRs (MFMA A/B frag)
typedef __attribute__((ext_vector_type(4))) float f32x4;    // MFMA C/D frag

#define DEV static __device__ __forceinline__

DEV float bf2f(u16 b){ union{unsigned u; float f;} c; c.u = ((unsigned)b) << 16; return c.f; }
DEV u16 f2bf(float f){ union{float f; unsigned u;} c; c.f = f; unsigned u = c.u; u += 0x7FFF + ((u >> 16) & 1); return (u16)(u >> 16); }
// compiler-cast path: pairs of these fold to v_cvt_pk_bf16_f32 (RNE)
DEV u16 f2bfh(float f){ union { __hip_bfloat16 h; u16 u; } c; c.h = __float2bfloat16(f); return c.u; }
// constant-foldable float4 component extract (c is compile-time after unroll)
DEV float getc(float4 v, int c){ return c == 0 ? v.x : c == 1 ? v.y : c == 2 ? v.z : v.w; }

// async global->LDS, 16B per lane; LDS dest = wave-uniform base + lane*16
DEV void gload16(const void* g, void* l){
  __builtin_amdgcn_global_load_lds((const __attribute__((address_space(1))) unsigned int*)g,
                                   (__attribute__((address_space(3))) unsigned int*)l, 16, 0, 0);
}

// ---------------- RMSNorm + gating (one block per token), fp32 in, bf16 t out ----------------
__global__ __launch_bounds__(256) void k_rms(
    const float* __restrict__ x, const float* __restrict__ nsc,
    const float* __restrict__ gw, const float* __restrict__ gb,
    u16* __restrict__ t, int* __restrict__ topi, float* __restrict__ topp)
{
  const int token = blockIdx.x, tid = threadIdx.x;
  const int wv = tid >> 6, lane = tid & 63;
  const float4 xv = *(const float4*)&x[(size_t)token * 1024 + tid * 4];
  float f[4] = {xv.x, xv.y, xv.z, xv.w};
  float ss = f[0]*f[0] + f[1]*f[1] + f[2]*f[2] + f[3]*f[3];
  #pragma unroll
  for (int o = 32; o > 0; o >>= 1) ss += __shfl_down(ss, o, 64);
  __shared__ float red[4];
  __shared__ float s_rs;
  if (lane == 0) red[wv] = ss;
  __syncthreads();
  if (tid == 0) s_rs = rsqrtf((red[0] + red[1] + red[2] + red[3]) * (1.0f / 1024.0f) + 1e-5f);
  __syncthreads();
  const float rs = s_rs;
  const float4 sv = *(const float4*)&nsc[tid * 4];
  const float sc[4] = {sv.x, sv.y, sv.z, sv.w};
  float tf[4]; u16x4 tv;
  #pragma unroll
  for (int j = 0; j < 4; ++j){ tf[j] = f[j] * rs * sc[j]; tv[j] = f2bf(tf[j]); }
  *(u16x4*)&t[(size_t)token * 1024 + tid * 4] = tv;

  // gate logits from fp32 t (pre-rounding): t @ gate_w[1024][8]
  float la[8] = {0,0,0,0,0,0,0,0};
  #pragma unroll
  for (int j = 0; j < 4; ++j){
    const int k = tid * 4 + j;
    const float4 g0 = *(const float4*)&gw[k * 8];
    const float4 g1 = *(const float4*)&gw[k * 8 + 4];
    la[0] += tf[j] * g0.x; la[1] += tf[j] * g0.y; la[2] += tf[j] * g0.z; la[3] += tf[j] * g0.w;
    la[4] += tf[j] * g1.x; la[5] += tf[j] * g1.y; la[6] += tf[j] * g1.z; la[7] += tf[j] * g1.w;
  }
  #pragma unroll
  for (int o = 32; o > 0; o >>= 1)
    #pragma unroll
    for (int e = 0; e < 8; ++e) la[e] += __shfl_down(la[e], o, 64);
  __shared__ float lred[4][8];
  if (lane == 0){
    #pragma unroll
    for (int e = 0; e < 8; ++e) lred[wv][e] = la[e];
  }
  __syncthreads();
  if (tid == 0){
    float lg[8];
    #pragma unroll
    for (int e = 0; e < 8; ++e) lg[e] = lred[0][e] + lred[1][e] + lred[2][e] + lred[3][e] + gb[e];
    int i0 = 0;
    for (int e = 1; e < 8; ++e) if (lg[e] > lg[i0]) i0 = e;       // ties -> lower index (top_k semantics)
    int i1 = -1;
    for (int e = 0; e < 8; ++e) if (e != i0 && (i1 < 0 || lg[e] > lg[i1])) i1 = e;
    const float d = __expf(lg[i1] - lg[i0]);
    const float p0 = 1.0f / (1.0f + d);
    topi[token * 2] = i0; topi[token * 2 + 1] = i1;
    topp[token * 2] = p0; topp[token * 2 + 1] = d * p0;
  }
}

// ---------------- routing: bucket assignments per expert ----------------
__global__ __launch_bounds__(256) void k_route(
    const int* __restrict__ topi, const float* __restrict__ topp,
    int* __restrict__ cnt, int* __restrict__ offs, int* __restrict__ tok_of,
    float* __restrict__ wt_of, int* __restrict__ slot_of, int* __restrict__ posg)
{
  __shared__ int c[8];
  __shared__ int o[8];
  const int tid = threadIdx.x;
  if (tid < 8) c[tid] = 0;
  __syncthreads();
  for (int a = tid; a < 4096; a += 256){
    int e = topi[a];
    posg[a] = atomicAdd(&c[e], 1);
  }
  __syncthreads();
  if (tid == 0){
    int run = 0;
    for (int e = 0; e < 8; ++e){ o[e] = run; offs[e] = run; cnt[e] = c[e]; run += c[e]; }
  }
  __syncthreads();
  for (int a = tid; a < 4096; a += 256){
    int e = topi[a];
    int s = o[e] + posg[a];
    tok_of[s] = a >> 1;
    wt_of[s] = topp[a];
    slot_of[a] = s;
  }
}

// ---------------- grouped GEMM1: h = swiglu(t @ w1 + b1) ----------------
// 128x128 tile, BK=64, SINGLE buffer (round-3-proven: smaller LDS beats dbuf
// in this latency-bound regime). XCD-locality swizzle: dispatch id D executes
// logical L=(D&7)*512+(D>>3); logical order = m-fastest, so each XCD owns one
// expert and consecutive blocks on an XCD share one w1 panel -> L2-hit reuse.
// A: bf16 t via global_load_lds, pre-swizzled source (unit ^= row&7).
// B: fused fp32 w1 [K][N] -> float4 reg loads -> bf16 -> transposed swizzled ds_write.
__global__ __launch_bounds__(256) void k_gemm1(
    const u16* __restrict__ t, const float* __restrict__ w1, const float* __restrict__ b1,
    const int* __restrict__ cnt, const int* __restrict__ offs, const int* __restrict__ tok_of,
    u16* __restrict__ h)
{
  const int fid = blockIdx.x + (blockIdx.y << 5) + (blockIdx.z << 9);  // dispatch-linear, grid 32x16x8=4096
  const int L = ((fid & 7) << 9) + (fid >> 3);                         // bijective: XCD = fid&7 owns L in [xcd*512, +512)
  const int e = L >> 9;                    // expert (one per XCD)
  const int n0 = ((L >> 4) & 31) * 128;    // n-panel
  const int m0 = (L & 15) * 128;           // m fastest -> panel sharers adjacent
  const int count = cnt[e];
  if (m0 >= count) return;
  const int off = offs[e];

  __shared__ __attribute__((aligned(16))) u16 As[128 * 64];   // 16 KiB
  __shared__ __attribute__((aligned(16))) u16 Bs[128 * 64];   // 16 KiB, [n][k] bf16

  const int tid = threadIdx.x, wv = tid >> 6, lane = tid & 63;
  const int arl = lane >> 3;          // row within 8-row stage group == row&7
  const int axu = (lane & 7) ^ arl;   // pre-swizzled source unit (XOR involution)

  const u16* asrc[4];
  u16* adst[4];
  #pragma unroll
  for (int i = 0; i < 4; ++i){
    const int rr = i * 32 + wv * 8 + arl;
    int r = m0 + rr; if (r > count - 1) r = count - 1;
    asrc[i] = t + (size_t)tok_of[off + r] * 1024 + axu * 8;
    adst[i] = &As[(i * 32 + wv * 8) * 64];
  }

  // B staging map: thread covers k = tkq*8 .. tkq*8+7 (contiguous), n = tnb..tnb+3
  const int tkq = tid >> 5;           // 0..7  (16B k-chunk)
  const int tnb = (tid & 31) * 4;     // 0..124
  const float* bsrc = w1 + (size_t)e * (1024 * 4096) + (size_t)(tkq * 8) * 4096 + n0 + tnb;

  const int wm = wv & 1, wn = wv >> 1;
  const int fr = lane & 15, q = lane >> 4;

  f32x4 acc[4][4];
  #pragma unroll
  for (int a = 0; a < 4; ++a)
    #pragma unroll
    for (int b = 0; b < 4; ++b) acc[a][b] = (f32x4){0.f, 0.f, 0.f, 0.f};

  for (int k0 = 0; k0 < 1024; k0 += 64){
    #pragma unroll
    for (int i = 0; i < 4; ++i){ gload16(asrc[i], adst[i]); asrc[i] += 64; }
    const float4 fv0 = *(const float4*)(bsrc);
    const float4 fv1 = *(const float4*)(bsrc + 4096);
    const float4 fv2 = *(const float4*)(bsrc + 2 * 4096);
    const float4 fv3 = *(const float4*)(bsrc + 3 * 4096);
    const float4 fv4 = *(const float4*)(bsrc + 4 * 4096);
    const float4 fv5 = *(const float4*)(bsrc + 5 * 4096);
    const float4 fv6 = *(const float4*)(bsrc + 6 * 4096);
    const float4 fv7 = *(const float4*)(bsrc + 7 * 4096);
    bsrc += (size_t)64 * 4096;
    #pragma unroll
    for (int c = 0; c < 4; ++c){
      const int nr = tnb + c;
      u16x8 wq;
      wq[0] = f2bfh(getc(fv0, c)); wq[1] = f2bfh(getc(fv1, c));
      wq[2] = f2bfh(getc(fv2, c)); wq[3] = f2bfh(getc(fv3, c));
      wq[4] = f2bfh(getc(fv4, c)); wq[5] = f2bfh(getc(fv5, c));
      wq[6] = f2bfh(getc(fv6, c)); wq[7] = f2bfh(getc(fv7, c));
      *(u16x8*)((char*)Bs + nr * 128 + ((tkq ^ ((nr >> 1) & 7)) << 4)) = wq;
    }
    __syncthreads();
    #pragma unroll
    for (int hh = 0; hh < 2; ++hh){
      const int puA = (((hh * 4) + q) ^ (fr & 7)) * 8;
      const int puB = (((hh * 4) + q) ^ ((fr >> 1) & 7)) * 8;
      bf16x8 af[4], bq[4];
      #pragma unroll
      for (int fm = 0; fm < 4; ++fm) af[fm] = *(const bf16x8*)&As[(wm * 64 + fm * 16 + fr) * 64 + puA];
      #pragma unroll
      for (int fn = 0; fn < 4; ++fn) bq[fn] = *(const bf16x8*)&Bs[(wn * 64 + fn * 16 + fr) * 64 + puB];
      #pragma unroll
      for (int fm = 0; fm < 4; ++fm)
        #pragma unroll
        for (int fn = 0; fn < 4; ++fn)
          acc[fm][fn] = __builtin_amdgcn_mfma_f32_16x16x32_bf16(af[fm], bq[fn], acc[fm][fn], 0, 0, 0);
    }
    __syncthreads();
  }

  // epilogue: +b1, interleaved SwiGLU (even col = glu, odd = lin), store h[slot][col/2]
  const int cb = n0 + wn * 64 + fr;
  float b1v[4];
  #pragma unroll
  for (int fn = 0; fn < 4; ++fn) b1v[fn] = b1[e * 4096 + cb + fn * 16];
  const int rq = q * 4;
  const bool ev = ((lane & 1) == 0);
  #pragma unroll
  for (int fm = 0; fm < 4; ++fm)
    #pragma unroll
    for (int fn = 0; fn < 4; ++fn)
      #pragma unroll
      for (int r = 0; r < 4; ++r){
        const float val = acc[fm][fn][r] + b1v[fn];
        const float oth = __shfl_xor(val, 1, 64);
        if (ev){
          const int row = m0 + wm * 64 + fm * 16 + rq + r;
          if (row < count){
            const float g = fminf(val, 7.0f);
            const float l = fminf(fmaxf(oth, -7.0f), 7.0f);
            const float o = g / (1.0f + __expf(-1.702f * g)) * (l + 1.0f);
            h[(size_t)(off + row) * 2048 + ((cb + fn * 16) >> 1)] = f2bf(o);
          }
        }
      }
}

// ---------------- grouped GEMM2: ys = (h @ w2 + b2) * gate_wt ----------------
// 128x64 tile, BK=64, double-buffered (round-4 net-positive for gemm2).
// Same XCD-locality swizzle, grid 16x16x8 = 2048.
__global__ __launch_bounds__(256) void k_gemm2(
    const u16* __restrict__ h, const float* __restrict__ w2, const float* __restrict__ b2,
    const int* __restrict__ cnt, const int* __restrict__ offs, const float* __restrict__ wt_of,
    u16* __restrict__ ys)
{
  const int fid = blockIdx.x + (blockIdx.y << 4) + (blockIdx.z << 8);  // grid 16x16x8=2048
  const int L = ((fid & 7) << 8) + (fid >> 3);                         // XCD = fid&7 owns L in [xcd*256, +256)
  const int e = L >> 8;
  const int n0 = ((L >> 4) & 15) * 64;
  const int m0 = (L & 15) * 128;
  const int count = cnt[e];
  if (m0 >= count) return;
  const int off = offs[e];

  __shared__ __attribute__((aligned(16))) u16 As[2][128 * 64];   // 32 KiB
  __shared__ __attribute__((aligned(16))) u16 Bs[2][64 * 64];    // 16 KiB, [n][k] bf16

  const int tid = threadIdx.x, wv = tid >> 6, lane = tid & 63;
  const int arl = lane >> 3;
  const int axu = (lane & 7) ^ arl;

  const u16* asrc[4];
  u16* adst[2][4];
  #pragma unroll
  for (int i = 0; i < 4; ++i){
    const int rr = i * 32 + wv * 8 + arl;
    int r = m0 + rr; if (r > count - 1) r = count - 1;
    asrc[i] = h + (size_t)(off + r) * 2048 + axu * 8;
    adst[0][i] = &As[0][(i * 32 + wv * 8) * 64];
    adst[1][i] = &As[1][(i * 32 + wv * 8) * 64];
  }

  // B staging map: thread covers k = tkq*4 .. tkq*4+3, n = tnb..tnb+3
  const int tkq = tid >> 4;          // 0..15 (8B k-chunk)
  const int tnb = (tid & 15) * 4;    // 0..60
  const float* bsrc = w2 + (size_t)e * (2048 * 1024) + (size_t)(tkq * 4) * 1024 + n0 + tnb;

  const int wm = wv & 1, wn = wv >> 1;
  const int fr = lane & 15, q = lane >> 4;

  f32x4 acc[4][2];
  #pragma unroll
  for (int a = 0; a < 4; ++a)
    #pragma unroll
    for (int b = 0; b < 2; ++b) acc[a][b] = (f32x4){0.f, 0.f, 0.f, 0.f};

  auto loadB = [&](float4* fv){
    #pragma unroll
    for (int j = 0; j < 4; ++j) fv[j] = *(const float4*)(bsrc + (size_t)j * 1024);
    bsrc += (size_t)64 * 1024;
  };
  auto writeB = [&](u16* B, const float4* fv){
    #pragma unroll
    for (int c = 0; c < 4; ++c){
      const int nr = tnb + c;
      u16x4 wd;
      wd[0] = f2bfh(getc(fv[0], c)); wd[1] = f2bfh(getc(fv[1], c));
      wd[2] = f2bfh(getc(fv[2], c)); wd[3] = f2bfh(getc(fv[3], c));
      *(u16x4*)((char*)B + nr * 128 + (((tkq >> 1) ^ ((nr >> 1) & 7)) << 4) + ((tkq & 1) << 3)) = wd;
    }
  };
  auto compute = [&](const u16* A, const u16* B){
    #pragma unroll
    for (int hh = 0; hh < 2; ++hh){
      const int puA = (((hh * 4) + q) ^ (fr & 7)) * 8;
      const int puB = (((hh * 4) + q) ^ ((fr >> 1) & 7)) * 8;
      bf16x8 af[4], bq[2];
      #pragma unroll
      for (int fm = 0; fm < 4; ++fm) af[fm] = *(const bf16x8*)&A[(wm * 64 + fm * 16 + fr) * 64 + puA];
      #pragma unroll
      for (int fn = 0; fn < 2; ++fn) bq[fn] = *(const bf16x8*)&B[(wn * 32 + fn * 16 + fr) * 64 + puB];
      #pragma unroll
      for (int fm = 0; fm < 4; ++fm)
        #pragma unroll
        for (int fn = 0; fn < 2; ++fn)
          acc[fm][fn] = __builtin_amdgcn_mfma_f32_16x16x32_bf16(af[fm], bq[fn], acc[fm][fn], 0, 0, 0);
    }
  };

  // prologue: stage tile 0
  {
    #pragma unroll
    for (int i = 0; i < 4; ++i){ gload16(asrc[i], adst[0][i]); asrc[i] += 64; }
    float4 fv[4];
    loadB(fv);
    writeB(Bs[0], fv);
  }
  __syncthreads();

  int cur = 0;
  for (int tt = 0; tt < 31; ++tt){
    const int nxt = cur ^ 1;
    #pragma unroll
    for (int i = 0; i < 4; ++i){ gload16(asrc[i], adst[nxt][i]); asrc[i] += 64; }
    float4 fv[4];
    loadB(fv);
    compute(As[cur], Bs[cur]);
    writeB(Bs[nxt], fv);
    __syncthreads();
    cur = nxt;
  }
  compute(As[cur], Bs[cur]);

  const int cb = n0 + wn * 32 + fr;
  float b2v[2];
  #pragma unroll
  for (int fn = 0; fn < 2; ++fn) b2v[fn] = b2[e * 1024 + cb + fn * 16];
  const int rq = q * 4;
  #pragma unroll
  for (int fm = 0; fm < 4; ++fm)
    #pragma unroll
    for (int rr = 0; rr < 4; ++rr){
      const int row = m0 + wm * 64 + fm * 16 + rq + rr;
      if (row < count){
        const float wt = wt_of[off + row];
        #pragma unroll
        for (int fn = 0; fn < 2; ++fn){
          const float v = (acc[fm][fn][rr] + b2v[fn]) * wt;
          ys[(size_t)(off + row) * 1024 + cb + fn * 16] = f2bf(v);
        }
      }
    }
}

// ---------------- final: out = x + ys[slot0] + ys[slot1], fp32 out ----------------
__global__ __launch_bounds__(256) void k_final(
    const float* __restrict__ x, const u16* __restrict__ ys,
    const int* __restrict__ slot_of, float* __restrict__ out)
{
  const int gid = blockIdx.x * 256 + threadIdx.x;
  const int token = gid >> 8;
  const int c0 = (gid & 255) * 4;
  const int s0 = slot_of[token * 2], s1 = slot_of[token * 2 + 1];
  const float4 xv = *(const float4*)&x[(size_t)token * 1024 + c0];
  const u16x4 y0 = *(const u16x4*)&ys[(size_t)s0 * 1024 + c0];
  const u16x4 y1 = *(const u16x4*)&ys[(size_t)s1 * 1024 + c0];
  float4 o;
  o.x = xv.x + bf2f(y0[0]) + bf2f(y1[0]);
  o.y = xv.y + bf2f(y0[1]) + bf2f(y1[1]);
  o.z = xv.z + bf2f(y0[2]) + bf2f(y1[2]);
  o.w = xv.w + bf2f(y0[3]) + bf2f(y1[3]);
  *(float4*)&out[(size_t)token * 1024 + c0] = o;
}

extern "C" void kernel_launch(void* const* d_in, const int* in_sizes, int n_in,
                              void* d_out, int out_size, void* d_ws, size_t ws_size,
                              hipStream_t stream)
{
  const float* x   = (const float*)d_in[0];
  const float* nsc = (const float*)d_in[1];
  const float* gw  = (const float*)d_in[2];
  const float* gb  = (const float*)d_in[3];
  const float* w1  = (const float*)d_in[4];
  const float* b1  = (const float*)d_in[5];
  const float* w2  = (const float*)d_in[6];
  const float* b2  = (const float*)d_in[7];
  float* out = (float*)d_out;
  char* ws = (char*)d_ws;

  size_t o = 0;
  auto alloc = [&](size_t bytes){ size_t r = o; o = (o + bytes + 255) & ~(size_t)255; return r; };
  const size_t o_t    = alloc((size_t)2048 * 1024 * 2);        // t bf16
  const size_t o_h    = alloc((size_t)4096 * 2048 * 2);        // swiglu output bf16
  const size_t o_ys   = alloc((size_t)4096 * 1024 * 2);        // per-slot expert output bf16
  const size_t o_topi = alloc(4096 * 4);
  const size_t o_topp = alloc(4096 * 4);
  const size_t o_posg = alloc(4096 * 4);
  const size_t o_tok  = alloc(4096 * 4);
  const size_t o_wt   = alloc(4096 * 4);
  const size_t o_slot = alloc(4096 * 4);
  const size_t o_cnt  = alloc(8 * 4);
  const size_t o_offs = alloc(8 * 4);
  if (ws_size < o) return;  // ws too small -> output stays zero (diagnostic: absmax == 5.28125)

  u16*   t_ws  = (u16*)(ws + o_t);
  u16*   h_ws  = (u16*)(ws + o_h);
  u16*   ys    = (u16*)(ws + o_ys);
  int*   topi  = (int*)(ws + o_topi);
  float* topp  = (float*)(ws + o_topp);
  int*   posg  = (int*)(ws + o_posg);
  int*   tok   = (int*)(ws + o_tok);
  float* wt    = (float*)(ws + o_wt);
  int*   slot  = (int*)(ws + o_slot);
  int*   cnt   = (int*)(ws + o_cnt);
  int*   offs  = (int*)(ws + o_offs);

  k_rms  <<<2048, 256, 0, stream>>>(x, nsc, gw, gb, t_ws, topi, topp);
  k_route<<<1, 256, 0, stream>>>(topi, topp, cnt, offs, tok, wt, slot, posg);
  k_gemm1<<<dim3(32, 16, 8), 256, 0, stream>>>(t_ws, w1, b1, cnt, offs, tok, h_ws);
  k_gemm2<<<dim3(16, 16, 8), 256, 0, stream>>>(h_ws, w2, b2, cnt, offs, wt, ys);
  k_final<<<2048, 256, 0, stream>>>(x, ys, slot, out);
}

// Round 6
// 394.080 us; speedup vs baseline: 1.0932x; 1.0932x over previous
//
#include <hip/hip_runtime.h>
#include <hip/hip_bf16.h>

typedef unsigned short u16;
typedef __attribute__((ext_vector_type(4))) unsigned short u16x4;
typedef __attribute__((ext_vector_type(8))) unsigned short u16x8;
typedef __attribute__((ext_vector_type(8))) short bf16x8;   // 8 bf16 = 4 VGPRs (MFMA A/B frag)
typedef __attribute__((ext_vector_type(4))) float f32x4;    // MFMA C/D frag

#define DEV static __device__ __forceinline__

DEV float bf2f(u16 b){ union{unsigned u; float f;} c; c.u = ((unsigned)b) << 16; return c.f; }
DEV u16 f2bf(float f){ union{float f; unsigned u;} c; c.f = f; unsigned u = c.u; u += 0x7FFF + ((u >> 16) & 1); return (u16)(u >> 16); }
// compiler-cast path: pairs of these fold to v_cvt_pk_bf16_f32 (RNE)
DEV u16 f2bfh(float f){ union { __hip_bfloat16 h; u16 u; } c; c.h = __float2bfloat16(f); return c.u; }
// constant-foldable float4 component extract (c is compile-time after unroll)
DEV float getc(float4 v, int c){ return c == 0 ? v.x : c == 1 ? v.y : c == 2 ? v.z : v.w; }

// async global->LDS, 16B per lane; LDS dest = wave-uniform base + lane*16
DEV void gload16(const void* g, void* l){
  __builtin_amdgcn_global_load_lds((const __attribute__((address_space(1))) unsigned int*)g,
                                   (__attribute__((address_space(3))) unsigned int*)l, 16, 0, 0);
}

// ---------------- RMSNorm + gating (one block per token), fp32 in, bf16 t out ----------------
__global__ __launch_bounds__(256) void k_rms(
    const float* __restrict__ x, const float* __restrict__ nsc,
    const float* __restrict__ gw, const float* __restrict__ gb,
    u16* __restrict__ t, int* __restrict__ topi, float* __restrict__ topp)
{
  const int token = blockIdx.x, tid = threadIdx.x;
  const int wv = tid >> 6, lane = tid & 63;
  const float4 xv = *(const float4*)&x[(size_t)token * 1024 + tid * 4];
  float f[4] = {xv.x, xv.y, xv.z, xv.w};
  float ss = f[0]*f[0] + f[1]*f[1] + f[2]*f[2] + f[3]*f[3];
  #pragma unroll
  for (int o = 32; o > 0; o >>= 1) ss += __shfl_down(ss, o, 64);
  __shared__ float red[4];
  __shared__ float s_rs;
  if (lane == 0) red[wv] = ss;
  __syncthreads();
  if (tid == 0) s_rs = rsqrtf((red[0] + red[1] + red[2] + red[3]) * (1.0f / 1024.0f) + 1e-5f);
  __syncthreads();
  const float rs = s_rs;
  const float4 sv = *(const float4*)&nsc[tid * 4];
  const float sc[4] = {sv.x, sv.y, sv.z, sv.w};
  float tf[4]; u16x4 tv;
  #pragma unroll
  for (int j = 0; j < 4; ++j){ tf[j] = f[j] * rs * sc[j]; tv[j] = f2bf(tf[j]); }
  *(u16x4*)&t[(size_t)token * 1024 + tid * 4] = tv;

  // gate logits from fp32 t (pre-rounding): t @ gate_w[1024][8]
  float la[8] = {0,0,0,0,0,0,0,0};
  #pragma unroll
  for (int j = 0; j < 4; ++j){
    const int k = tid * 4 + j;
    const float4 g0 = *(const float4*)&gw[k * 8];
    const float4 g1 = *(const float4*)&gw[k * 8 + 4];
    la[0] += tf[j] * g0.x; la[1] += tf[j] * g0.y; la[2] += tf[j] * g0.z; la[3] += tf[j] * g0.w;
    la[4] += tf[j] * g1.x; la[5] += tf[j] * g1.y; la[6] += tf[j] * g1.z; la[7] += tf[j] * g1.w;
  }
  #pragma unroll
  for (int o = 32; o > 0; o >>= 1)
    #pragma unroll
    for (int e = 0; e < 8; ++e) la[e] += __shfl_down(la[e], o, 64);
  __shared__ float lred[4][8];
  if (lane == 0){
    #pragma unroll
    for (int e = 0; e < 8; ++e) lred[wv][e] = la[e];
  }
  __syncthreads();
  if (tid == 0){
    float lg[8];
    #pragma unroll
    for (int e = 0; e < 8; ++e) lg[e] = lred[0][e] + lred[1][e] + lred[2][e] + lred[3][e] + gb[e];
    int i0 = 0;
    for (int e = 1; e < 8; ++e) if (lg[e] > lg[i0]) i0 = e;       // ties -> lower index (top_k semantics)
    int i1 = -1;
    for (int e = 0; e < 8; ++e) if (e != i0 && (i1 < 0 || lg[e] > lg[i1])) i1 = e;
    const float d = __expf(lg[i1] - lg[i0]);
    const float p0 = 1.0f / (1.0f + d);
    topi[token * 2] = i0; topi[token * 2 + 1] = i1;
    topp[token * 2] = p0; topp[token * 2 + 1] = d * p0;
  }
}

// ---------------- routing: bucket assignments per expert ----------------
__global__ __launch_bounds__(256) void k_route(
    const int* __restrict__ topi, const float* __restrict__ topp,
    int* __restrict__ cnt, int* __restrict__ offs, int* __restrict__ tok_of,
    float* __restrict__ wt_of, int* __restrict__ slot_of, int* __restrict__ posg)
{
  __shared__ int c[8];
  __shared__ int o[8];
  const int tid = threadIdx.x;
  if (tid < 8) c[tid] = 0;
  __syncthreads();
  for (int a = tid; a < 4096; a += 256){
    int e = topi[a];
    posg[a] = atomicAdd(&c[e], 1);
  }
  __syncthreads();
  if (tid == 0){
    int run = 0;
    for (int e = 0; e < 8; ++e){ o[e] = run; offs[e] = run; cnt[e] = c[e]; run += c[e]; }
  }
  __syncthreads();
  for (int a = tid; a < 4096; a += 256){
    int e = topi[a];
    int s = o[e] + posg[a];
    tok_of[s] = a >> 1;
    wt_of[s] = topp[a];
    slot_of[a] = s;
  }
}

// ---------------- grouped GEMM1: h = swiglu(t @ w1 + b1) ----------------
// 128x128 tile, BK=64, SINGLE buffer (round-3-proven config, default order).
// A: bf16 t via global_load_lds, pre-swizzled source (unit ^= row&7).
// B: fused fp32 w1 [K][N] -> float4 reg loads -> bf16 -> transposed swizzled ds_write.
__global__ __launch_bounds__(256) void k_gemm1(
    const u16* __restrict__ t, const float* __restrict__ w1, const float* __restrict__ b1,
    const int* __restrict__ cnt, const int* __restrict__ offs, const int* __restrict__ tok_of,
    u16* __restrict__ h)
{
  const int e = blockIdx.z;
  const int count = cnt[e];
  const int m0 = blockIdx.y * 128;
  if (m0 >= count) return;
  const int off = offs[e];
  const int n0 = blockIdx.x * 128;

  __shared__ __attribute__((aligned(16))) u16 As[128 * 64];   // 16 KiB
  __shared__ __attribute__((aligned(16))) u16 Bs[128 * 64];   // 16 KiB, [n][k] bf16

  const int tid = threadIdx.x, wv = tid >> 6, lane = tid & 63;
  const int arl = lane >> 3;          // row within 8-row stage group == row&7
  const int axu = (lane & 7) ^ arl;   // pre-swizzled source unit (XOR involution)

  const u16* asrc[4];
  u16* adst[4];
  #pragma unroll
  for (int i = 0; i < 4; ++i){
    const int rr = i * 32 + wv * 8 + arl;
    int r = m0 + rr; if (r > count - 1) r = count - 1;
    asrc[i] = t + (size_t)tok_of[off + r] * 1024 + axu * 8;
    adst[i] = &As[(i * 32 + wv * 8) * 64];
  }

  // B staging map: thread covers k = tkq*8 .. tkq*8+7 (contiguous), n = tnb..tnb+3
  const int tkq = tid >> 5;           // 0..7  (16B k-chunk)
  const int tnb = (tid & 31) * 4;     // 0..124
  const float* bsrc = w1 + (size_t)e * (1024 * 4096) + (size_t)(tkq * 8) * 4096 + n0 + tnb;

  const int wm = wv & 1, wn = wv >> 1;
  const int fr = lane & 15, q = lane >> 4;

  f32x4 acc[4][4];
  #pragma unroll
  for (int a = 0; a < 4; ++a)
    #pragma unroll
    for (int b = 0; b < 4; ++b) acc[a][b] = (f32x4){0.f, 0.f, 0.f, 0.f};

  for (int k0 = 0; k0 < 1024; k0 += 64){
    #pragma unroll
    for (int i = 0; i < 4; ++i){ gload16(asrc[i], adst[i]); asrc[i] += 64; }
    const float4 fv0 = *(const float4*)(bsrc);
    const float4 fv1 = *(const float4*)(bsrc + 4096);
    const float4 fv2 = *(const float4*)(bsrc + 2 * 4096);
    const float4 fv3 = *(const float4*)(bsrc + 3 * 4096);
    const float4 fv4 = *(const float4*)(bsrc + 4 * 4096);
    const float4 fv5 = *(const float4*)(bsrc + 5 * 4096);
    const float4 fv6 = *(const float4*)(bsrc + 6 * 4096);
    const float4 fv7 = *(const float4*)(bsrc + 7 * 4096);
    bsrc += (size_t)64 * 4096;
    #pragma unroll
    for (int c = 0; c < 4; ++c){
      const int nr = tnb + c;
      u16x8 wq;
      wq[0] = f2bfh(getc(fv0, c)); wq[1] = f2bfh(getc(fv1, c));
      wq[2] = f2bfh(getc(fv2, c)); wq[3] = f2bfh(getc(fv3, c));
      wq[4] = f2bfh(getc(fv4, c)); wq[5] = f2bfh(getc(fv5, c));
      wq[6] = f2bfh(getc(fv6, c)); wq[7] = f2bfh(getc(fv7, c));
      *(u16x8*)((char*)Bs + nr * 128 + ((tkq ^ ((nr >> 1) & 7)) << 4)) = wq;
    }
    __syncthreads();
    #pragma unroll
    for (int hh = 0; hh < 2; ++hh){
      const int puA = (((hh * 4) + q) ^ (fr & 7)) * 8;
      const int puB = (((hh * 4) + q) ^ ((fr >> 1) & 7)) * 8;
      bf16x8 af[4], bq[4];
      #pragma unroll
      for (int fm = 0; fm < 4; ++fm) af[fm] = *(const bf16x8*)&As[(wm * 64 + fm * 16 + fr) * 64 + puA];
      #pragma unroll
      for (int fn = 0; fn < 4; ++fn) bq[fn] = *(const bf16x8*)&Bs[(wn * 64 + fn * 16 + fr) * 64 + puB];
      #pragma unroll
      for (int fm = 0; fm < 4; ++fm)
        #pragma unroll
        for (int fn = 0; fn < 4; ++fn)
          acc[fm][fn] = __builtin_amdgcn_mfma_f32_16x16x32_bf16(af[fm], bq[fn], acc[fm][fn], 0, 0, 0);
    }
    __syncthreads();
  }

  // epilogue: +b1, interleaved SwiGLU (even col = glu, odd = lin), store h[slot][col/2]
  const int cb = n0 + wn * 64 + fr;
  float b1v[4];
  #pragma unroll
  for (int fn = 0; fn < 4; ++fn) b1v[fn] = b1[e * 4096 + cb + fn * 16];
  const int rq = q * 4;
  const bool ev = ((lane & 1) == 0);
  #pragma unroll
  for (int fm = 0; fm < 4; ++fm)
    #pragma unroll
    for (int fn = 0; fn < 4; ++fn)
      #pragma unroll
      for (int r = 0; r < 4; ++r){
        const float val = acc[fm][fn][r] + b1v[fn];
        const float oth = __shfl_xor(val, 1, 64);
        if (ev){
          const int row = m0 + wm * 64 + fm * 16 + rq + r;
          if (row < count){
            const float g = fminf(val, 7.0f);
            const float l = fminf(fmaxf(oth, -7.0f), 7.0f);
            const float o = g / (1.0f + __expf(-1.702f * g)) * (l + 1.0f);
            h[(size_t)(off + row) * 2048 + ((cb + fn * 16) >> 1)] = f2bf(o);
          }
        }
      }
}

// ---------------- grouped GEMM2: ys = (h @ w2 + b2) * gate_wt ----------------
// 128x128 tile, BK=64, single buffer — byte-for-byte gemm1's proven loop with
// K=2048 and a plain epilogue. Doubles B arithmetic intensity vs old 128x64.
__global__ __launch_bounds__(256) void k_gemm2(
    const u16* __restrict__ h, const float* __restrict__ w2, const float* __restrict__ b2,
    const int* __restrict__ cnt, const int* __restrict__ offs, const float* __restrict__ wt_of,
    u16* __restrict__ ys)
{
  const int e = blockIdx.z;
  const int count = cnt[e];
  const int m0 = blockIdx.y * 128;
  if (m0 >= count) return;
  const int off = offs[e];
  const int n0 = blockIdx.x * 128;

  __shared__ __attribute__((aligned(16))) u16 As[128 * 64];   // 16 KiB
  __shared__ __attribute__((aligned(16))) u16 Bs[128 * 64];   // 16 KiB, [n][k] bf16

  const int tid = threadIdx.x, wv = tid >> 6, lane = tid & 63;
  const int arl = lane >> 3;
  const int axu = (lane & 7) ^ arl;

  const u16* asrc[4];
  u16* adst[4];
  #pragma unroll
  for (int i = 0; i < 4; ++i){
    const int rr = i * 32 + wv * 8 + arl;
    int r = m0 + rr; if (r > count - 1) r = count - 1;
    asrc[i] = h + (size_t)(off + r) * 2048 + axu * 8;
    adst[i] = &As[(i * 32 + wv * 8) * 64];
  }

  // B staging map: thread covers k = tkq*8 .. tkq*8+7 (contiguous), n = tnb..tnb+3
  const int tkq = tid >> 5;           // 0..7  (16B k-chunk)
  const int tnb = (tid & 31) * 4;     // 0..124
  const float* bsrc = w2 + (size_t)e * (2048 * 1024) + (size_t)(tkq * 8) * 1024 + n0 + tnb;

  const int wm = wv & 1, wn = wv >> 1;
  const int fr = lane & 15, q = lane >> 4;

  f32x4 acc[4][4];
  #pragma unroll
  for (int a = 0; a < 4; ++a)
    #pragma unroll
    for (int b = 0; b < 4; ++b) acc[a][b] = (f32x4){0.f, 0.f, 0.f, 0.f};

  for (int k0 = 0; k0 < 2048; k0 += 64){
    #pragma unroll
    for (int i = 0; i < 4; ++i){ gload16(asrc[i], adst[i]); asrc[i] += 64; }
    const float4 fv0 = *(const float4*)(bsrc);
    const float4 fv1 = *(const float4*)(bsrc + 1024);
    const float4 fv2 = *(const float4*)(bsrc + 2 * 1024);
    const float4 fv3 = *(const float4*)(bsrc + 3 * 1024);
    const float4 fv4 = *(const float4*)(bsrc + 4 * 1024);
    const float4 fv5 = *(const float4*)(bsrc + 5 * 1024);
    const float4 fv6 = *(const float4*)(bsrc + 6 * 1024);
    const float4 fv7 = *(const float4*)(bsrc + 7 * 1024);
    bsrc += (size_t)64 * 1024;
    #pragma unroll
    for (int c = 0; c < 4; ++c){
      const int nr = tnb + c;
      u16x8 wq;
      wq[0] = f2bfh(getc(fv0, c)); wq[1] = f2bfh(getc(fv1, c));
      wq[2] = f2bfh(getc(fv2, c)); wq[3] = f2bfh(getc(fv3, c));
      wq[4] = f2bfh(getc(fv4, c)); wq[5] = f2bfh(getc(fv5, c));
      wq[6] = f2bfh(getc(fv6, c)); wq[7] = f2bfh(getc(fv7, c));
      *(u16x8*)((char*)Bs + nr * 128 + ((tkq ^ ((nr >> 1) & 7)) << 4)) = wq;
    }
    __syncthreads();
    #pragma unroll
    for (int hh = 0; hh < 2; ++hh){
      const int puA = (((hh * 4) + q) ^ (fr & 7)) * 8;
      const int puB = (((hh * 4) + q) ^ ((fr >> 1) & 7)) * 8;
      bf16x8 af[4], bq[4];
      #pragma unroll
      for (int fm = 0; fm < 4; ++fm) af[fm] = *(const bf16x8*)&As[(wm * 64 + fm * 16 + fr) * 64 + puA];
      #pragma unroll
      for (int fn = 0; fn < 4; ++fn) bq[fn] = *(const bf16x8*)&Bs[(wn * 64 + fn * 16 + fr) * 64 + puB];
      #pragma unroll
      for (int fm = 0; fm < 4; ++fm)
        #pragma unroll
        for (int fn = 0; fn < 4; ++fn)
          acc[fm][fn] = __builtin_amdgcn_mfma_f32_16x16x32_bf16(af[fm], bq[fn], acc[fm][fn], 0, 0, 0);
    }
    __syncthreads();
  }

  // epilogue: +b2, scale by routing weight, store ys[slot][col]
  const int cb = n0 + wn * 64 + fr;
  float b2v[4];
  #pragma unroll
  for (int fn = 0; fn < 4; ++fn) b2v[fn] = b2[e * 1024 + cb + fn * 16];
  const int rq = q * 4;
  #pragma unroll
  for (int fm = 0; fm < 4; ++fm)
    #pragma unroll
    for (int rr = 0; rr < 4; ++rr){
      const int row = m0 + wm * 64 + fm * 16 + rq + rr;
      if (row < count){
        const float wt = wt_of[off + row];
        #pragma unroll
        for (int fn = 0; fn < 4; ++fn){
          const float v = (acc[fm][fn][rr] + b2v[fn]) * wt;
          ys[(size_t)(off + row) * 1024 + cb + fn * 16] = f2bf(v);
        }
      }
    }
}

// ---------------- final: out = x + ys[slot0] + ys[slot1], fp32 out ----------------
__global__ __launch_bounds__(256) void k_final(
    const float* __restrict__ x, const u16* __restrict__ ys,
    const int* __restrict__ slot_of, float* __restrict__ out)
{
  const int gid = blockIdx.x * 256 + threadIdx.x;
  const int token = gid >> 8;
  const int c0 = (gid & 255) * 4;
  const int s0 = slot_of[token * 2], s1 = slot_of[token * 2 + 1];
  const float4 xv = *(const float4*)&x[(size_t)token * 1024 + c0];
  const u16x4 y0 = *(const u16x4*)&ys[(size_t)s0 * 1024 + c0];
  const u16x4 y1 = *(const u16x4*)&ys[(size_t)s1 * 1024 + c0];
  float4 o;
  o.x = xv.x + bf2f(y0[0]) + bf2f(y1[0]);
  o.y = xv.y + bf2f(y0[1]) + bf2f(y1[1]);
  o.z = xv.z + bf2f(y0[2]) + bf2f(y1[2]);
  o.w = xv.w + bf2f(y0[3]) + bf2f(y1[3]);
  *(float4*)&out[(size_t)token * 1024 + c0] = o;
}

extern "C" void kernel_launch(void* const* d_in, const int* in_sizes, int n_in,
                              void* d_out, int out_size, void* d_ws, size_t ws_size,
                              hipStream_t stream)
{
  const float* x   = (const float*)d_in[0];
  const float* nsc = (const float*)d_in[1];
  const float* gw  = (const float*)d_in[2];
  const float* gb  = (const float*)d_in[3];
  const float* w1  = (const float*)d_in[4];
  const float* b1  = (const float*)d_in[5];
  const float* w2  = (const float*)d_in[6];
  const float* b2  = (const float*)d_in[7];
  float* out = (float*)d_out;
  char* ws = (char*)d_ws;

  size_t o = 0;
  auto alloc = [&](size_t bytes){ size_t r = o; o = (o + bytes + 255) & ~(size_t)255; return r; };
  const size_t o_t    = alloc((size_t)2048 * 1024 * 2);        // t bf16
  const size_t o_h    = alloc((size_t)4096 * 2048 * 2);        // swiglu output bf16
  const size_t o_ys   = alloc((size_t)4096 * 1024 * 2);        // per-slot expert output bf16
  const size_t o_topi = alloc(4096 * 4);
  const size_t o_topp = alloc(4096 * 4);
  const size_t o_posg = alloc(4096 * 4);
  const size_t o_tok  = alloc(4096 * 4);
  const size_t o_wt   = alloc(4096 * 4);
  const size_t o_slot = alloc(4096 * 4);
  const size_t o_cnt  = alloc(8 * 4);
  const size_t o_offs = alloc(8 * 4);
  if (ws_size < o) return;  // ws too small -> output stays zero (diagnostic: absmax == 5.28125)

  u16*   t_ws  = (u16*)(ws + o_t);
  u16*   h_ws  = (u16*)(ws + o_h);
  u16*   ys    = (u16*)(ws + o_ys);
  int*   topi  = (int*)(ws + o_topi);
  float* topp  = (float*)(ws + o_topp);
  int*   posg  = (int*)(ws + o_posg);
  int*   tok   = (int*)(ws + o_tok);
  float* wt    = (float*)(ws + o_wt);
  int*   slot  = (int*)(ws + o_slot);
  int*   cnt   = (int*)(ws + o_cnt);
  int*   offs  = (int*)(ws + o_offs);

  k_rms  <<<2048, 256, 0, stream>>>(x, nsc, gw, gb, t_ws, topi, topp);
  k_route<<<1, 256, 0, stream>>>(topi, topp, cnt, offs, tok, wt, slot, posg);
  k_gemm1<<<dim3(32, 16, 8), 256, 0, stream>>>(t_ws, w1, b1, cnt, offs, tok, h_ws);
  k_gemm2<<<dim3(8, 16, 8), 256, 0, stream>>>(h_ws, w2, b2, cnt, offs, wt, ys);
  k_final<<<2048, 256, 0, stream>>>(x, ys, slot, out);
}

// Round 7
// 361.086 us; speedup vs baseline: 1.1931x; 1.0914x over previous
//
#include <hip/hip_runtime.h>
#include <hip/hip_bf16.h>

typedef unsigned short u16;
typedef __attribute__((ext_vector_type(4))) unsigned short u16x4;
typedef __attribute__((ext_vector_type(8))) unsigned short u16x8;
typedef __attribute__((ext_vector_type(8))) short bf16x8;   // 8 bf16 = 4 VGPRs (MFMA A/B frag)
typedef __attribute__((ext_vector_type(4))) float f32x4;    // MFMA C/D frag

#define DEV static __device__ __forceinline__

DEV float bf2f(u16 b){ union{unsigned u; float f;} c; c.u = ((unsigned)b) << 16; return c.f; }
DEV u16 f2bf(float f){ union{float f; unsigned u;} c; c.f = f; unsigned u = c.u; u += 0x7FFF + ((u >> 16) & 1); return (u16)(u >> 16); }
// compiler-cast path: pairs of these fold to v_cvt_pk_bf16_f32 (RNE)
DEV u16 f2bfh(float f){ union { __hip_bfloat16 h; u16 u; } c; c.h = __float2bfloat16(f); return c.u; }
// constant-foldable float4 component extract (c is compile-time after unroll)
DEV float getc(float4 v, int c){ return c == 0 ? v.x : c == 1 ? v.y : c == 2 ? v.z : v.w; }

// async global->LDS, 16B per lane; LDS dest = wave-uniform base + lane*16
DEV void gload16(const void* g, void* l){
  __builtin_amdgcn_global_load_lds((const __attribute__((address_space(1))) unsigned int*)g,
                                   (__attribute__((address_space(3))) unsigned int*)l, 16, 0, 0);
}

// ---------------- RMSNorm + gating (one block per token), fp32 in, bf16 t out ----------------
__global__ __launch_bounds__(256) void k_rms(
    const float* __restrict__ x, const float* __restrict__ nsc,
    const float* __restrict__ gw, const float* __restrict__ gb,
    u16* __restrict__ t, int* __restrict__ topi, float* __restrict__ topp)
{
  const int token = blockIdx.x, tid = threadIdx.x;
  const int wv = tid >> 6, lane = tid & 63;
  const float4 xv = *(const float4*)&x[(size_t)token * 1024 + tid * 4];
  float f[4] = {xv.x, xv.y, xv.z, xv.w};
  float ss = f[0]*f[0] + f[1]*f[1] + f[2]*f[2] + f[3]*f[3];
  #pragma unroll
  for (int o = 32; o > 0; o >>= 1) ss += __shfl_down(ss, o, 64);
  __shared__ float red[4];
  __shared__ float s_rs;
  if (lane == 0) red[wv] = ss;
  __syncthreads();
  if (tid == 0) s_rs = rsqrtf((red[0] + red[1] + red[2] + red[3]) * (1.0f / 1024.0f) + 1e-5f);
  __syncthreads();
  const float rs = s_rs;
  const float4 sv = *(const float4*)&nsc[tid * 4];
  const float sc[4] = {sv.x, sv.y, sv.z, sv.w};
  float tf[4]; u16x4 tv;
  #pragma unroll
  for (int j = 0; j < 4; ++j){ tf[j] = f[j] * rs * sc[j]; tv[j] = f2bf(tf[j]); }
  *(u16x4*)&t[(size_t)token * 1024 + tid * 4] = tv;

  // gate logits from fp32 t (pre-rounding): t @ gate_w[1024][8]
  float la[8] = {0,0,0,0,0,0,0,0};
  #pragma unroll
  for (int j = 0; j < 4; ++j){
    const int k = tid * 4 + j;
    const float4 g0 = *(const float4*)&gw[k * 8];
    const float4 g1 = *(const float4*)&gw[k * 8 + 4];
    la[0] += tf[j] * g0.x; la[1] += tf[j] * g0.y; la[2] += tf[j] * g0.z; la[3] += tf[j] * g0.w;
    la[4] += tf[j] * g1.x; la[5] += tf[j] * g1.y; la[6] += tf[j] * g1.z; la[7] += tf[j] * g1.w;
  }
  #pragma unroll
  for (int o = 32; o > 0; o >>= 1)
    #pragma unroll
    for (int e = 0; e < 8; ++e) la[e] += __shfl_down(la[e], o, 64);
  __shared__ float lred[4][8];
  if (lane == 0){
    #pragma unroll
    for (int e = 0; e < 8; ++e) lred[wv][e] = la[e];
  }
  __syncthreads();
  if (tid == 0){
    float lg[8];
    #pragma unroll
    for (int e = 0; e < 8; ++e) lg[e] = lred[0][e] + lred[1][e] + lred[2][e] + lred[3][e] + gb[e];
    int i0 = 0;
    for (int e = 1; e < 8; ++e) if (lg[e] > lg[i0]) i0 = e;       // ties -> lower index (top_k semantics)
    int i1 = -1;
    for (int e = 0; e < 8; ++e) if (e != i0 && (i1 < 0 || lg[e] > lg[i1])) i1 = e;
    const float d = __expf(lg[i1] - lg[i0]);
    const float p0 = 1.0f / (1.0f + d);
    topi[token * 2] = i0; topi[token * 2 + 1] = i1;
    topp[token * 2] = p0; topp[token * 2 + 1] = d * p0;
  }
}

// ---------------- routing: bucket assignments per expert ----------------
__global__ __launch_bounds__(256) void k_route(
    const int* __restrict__ topi, const float* __restrict__ topp,
    int* __restrict__ cnt, int* __restrict__ offs, int* __restrict__ tok_of,
    float* __restrict__ wt_of, int* __restrict__ slot_of, int* __restrict__ posg)
{
  __shared__ int c[8];
  __shared__ int o[8];
  const int tid = threadIdx.x;
  if (tid < 8) c[tid] = 0;
  __syncthreads();
  for (int a = tid; a < 4096; a += 256){
    int e = topi[a];
    posg[a] = atomicAdd(&c[e], 1);
  }
  __syncthreads();
  if (tid == 0){
    int run = 0;
    for (int e = 0; e < 8; ++e){ o[e] = run; offs[e] = run; cnt[e] = c[e]; run += c[e]; }
  }
  __syncthreads();
  for (int a = tid; a < 4096; a += 256){
    int e = topi[a];
    int s = o[e] + posg[a];
    tok_of[s] = a >> 1;
    wt_of[s] = topp[a];
    slot_of[a] = s;
  }
}

// ---------------- grouped GEMM1: h = swiglu(t @ w1 + b1) ----------------
// 128x128 tile, BK=64, SINGLE buffer (round-3/6-proven config, 102us).
// A: bf16 t via global_load_lds, pre-swizzled source (unit ^= row&7).
// B: fused fp32 w1 [K][N] -> float4 reg loads -> bf16 -> transposed swizzled ds_write.
__global__ __launch_bounds__(256) void k_gemm1(
    const u16* __restrict__ t, const float* __restrict__ w1, const float* __restrict__ b1,
    const int* __restrict__ cnt, const int* __restrict__ offs, const int* __restrict__ tok_of,
    u16* __restrict__ h)
{
  const int e = blockIdx.z;
  const int count = cnt[e];
  const int m0 = blockIdx.y * 128;
  if (m0 >= count) return;
  const int off = offs[e];
  const int n0 = blockIdx.x * 128;

  __shared__ __attribute__((aligned(16))) u16 As[128 * 64];   // 16 KiB
  __shared__ __attribute__((aligned(16))) u16 Bs[128 * 64];   // 16 KiB, [n][k] bf16

  const int tid = threadIdx.x, wv = tid >> 6, lane = tid & 63;
  const int arl = lane >> 3;          // row within 8-row stage group == row&7
  const int axu = (lane & 7) ^ arl;   // pre-swizzled source unit (XOR involution)

  const u16* asrc[4];
  u16* adst[4];
  #pragma unroll
  for (int i = 0; i < 4; ++i){
    const int rr = i * 32 + wv * 8 + arl;
    int r = m0 + rr; if (r > count - 1) r = count - 1;
    asrc[i] = t + (size_t)tok_of[off + r] * 1024 + axu * 8;
    adst[i] = &As[(i * 32 + wv * 8) * 64];
  }

  // B staging map: thread covers k = tkq*8 .. tkq*8+7 (contiguous), n = tnb..tnb+3
  const int tkq = tid >> 5;           // 0..7  (16B k-chunk)
  const int tnb = (tid & 31) * 4;     // 0..124
  const float* bsrc = w1 + (size_t)e * (1024 * 4096) + (size_t)(tkq * 8) * 4096 + n0 + tnb;

  const int wm = wv & 1, wn = wv >> 1;
  const int fr = lane & 15, q = lane >> 4;

  f32x4 acc[4][4];
  #pragma unroll
  for (int a = 0; a < 4; ++a)
    #pragma unroll
    for (int b = 0; b < 4; ++b) acc[a][b] = (f32x4){0.f, 0.f, 0.f, 0.f};

  for (int k0 = 0; k0 < 1024; k0 += 64){
    #pragma unroll
    for (int i = 0; i < 4; ++i){ gload16(asrc[i], adst[i]); asrc[i] += 64; }
    const float4 fv0 = *(const float4*)(bsrc);
    const float4 fv1 = *(const float4*)(bsrc + 4096);
    const float4 fv2 = *(const float4*)(bsrc + 2 * 4096);
    const float4 fv3 = *(const float4*)(bsrc + 3 * 4096);
    const float4 fv4 = *(const float4*)(bsrc + 4 * 4096);
    const float4 fv5 = *(const float4*)(bsrc + 5 * 4096);
    const float4 fv6 = *(const float4*)(bsrc + 6 * 4096);
    const float4 fv7 = *(const float4*)(bsrc + 7 * 4096);
    bsrc += (size_t)64 * 4096;
    #pragma unroll
    for (int c = 0; c < 4; ++c){
      const int nr = tnb + c;
      u16x8 wq;
      wq[0] = f2bfh(getc(fv0, c)); wq[1] = f2bfh(getc(fv1, c));
      wq[2] = f2bfh(getc(fv2, c)); wq[3] = f2bfh(getc(fv3, c));
      wq[4] = f2bfh(getc(fv4, c)); wq[5] = f2bfh(getc(fv5, c));
      wq[6] = f2bfh(getc(fv6, c)); wq[7] = f2bfh(getc(fv7, c));
      *(u16x8*)((char*)Bs + nr * 128 + ((tkq ^ ((nr >> 1) & 7)) << 4)) = wq;
    }
    __syncthreads();
    #pragma unroll
    for (int hh = 0; hh < 2; ++hh){
      const int puA = (((hh * 4) + q) ^ (fr & 7)) * 8;
      const int puB = (((hh * 4) + q) ^ ((fr >> 1) & 7)) * 8;
      bf16x8 af[4], bq[4];
      #pragma unroll
      for (int fm = 0; fm < 4; ++fm) af[fm] = *(const bf16x8*)&As[(wm * 64 + fm * 16 + fr) * 64 + puA];
      #pragma unroll
      for (int fn = 0; fn < 4; ++fn) bq[fn] = *(const bf16x8*)&Bs[(wn * 64 + fn * 16 + fr) * 64 + puB];
      #pragma unroll
      for (int fm = 0; fm < 4; ++fm)
        #pragma unroll
        for (int fn = 0; fn < 4; ++fn)
          acc[fm][fn] = __builtin_amdgcn_mfma_f32_16x16x32_bf16(af[fm], bq[fn], acc[fm][fn], 0, 0, 0);
    }
    __syncthreads();
  }

  // epilogue: +b1, interleaved SwiGLU (even col = glu, odd = lin), store h[slot][col/2]
  const int cb = n0 + wn * 64 + fr;
  float b1v[4];
  #pragma unroll
  for (int fn = 0; fn < 4; ++fn) b1v[fn] = b1[e * 4096 + cb + fn * 16];
  const int rq = q * 4;
  const bool ev = ((lane & 1) == 0);
  #pragma unroll
  for (int fm = 0; fm < 4; ++fm)
    #pragma unroll
    for (int fn = 0; fn < 4; ++fn)
      #pragma unroll
      for (int r = 0; r < 4; ++r){
        const float val = acc[fm][fn][r] + b1v[fn];
        const float oth = __shfl_xor(val, 1, 64);
        if (ev){
          const int row = m0 + wm * 64 + fm * 16 + rq + r;
          if (row < count){
            const float g = fminf(val, 7.0f);
            const float l = fminf(fmaxf(oth, -7.0f), 7.0f);
            const float o = g / (1.0f + __expf(-1.702f * g)) * (l + 1.0f);
            h[(size_t)(off + row) * 2048 + ((cb + fn * 16) >> 1)] = f2bf(o);
          }
        }
      }
}

// ---------------- grouped GEMM2: ys = (h @ w2 + b2) * gate_wt ----------------
// 128x64 tile, BK=64, double-buffered (round-4-proven: one barrier/K-step,
// B fp32 loads genuinely in flight under MFMA). Verbatim r4 kernel.
__global__ __launch_bounds__(256) void k_gemm2(
    const u16* __restrict__ h, const float* __restrict__ w2, const float* __restrict__ b2,
    const int* __restrict__ cnt, const int* __restrict__ offs, const float* __restrict__ wt_of,
    u16* __restrict__ ys)
{
  const int e = blockIdx.z;
  const int count = cnt[e];
  const int m0 = blockIdx.y * 128;
  if (m0 >= count) return;
  const int off = offs[e];
  const int n0 = blockIdx.x * 64;

  __shared__ __attribute__((aligned(16))) u16 As[2][128 * 64];   // 32 KiB
  __shared__ __attribute__((aligned(16))) u16 Bs[2][64 * 64];    // 16 KiB, [n][k] bf16

  const int tid = threadIdx.x, wv = tid >> 6, lane = tid & 63;
  const int arl = lane >> 3;
  const int axu = (lane & 7) ^ arl;

  const u16* asrc[4];
  u16* adst[2][4];
  #pragma unroll
  for (int i = 0; i < 4; ++i){
    const int rr = i * 32 + wv * 8 + arl;
    int r = m0 + rr; if (r > count - 1) r = count - 1;
    asrc[i] = h + (size_t)(off + r) * 2048 + axu * 8;
    adst[0][i] = &As[0][(i * 32 + wv * 8) * 64];
    adst[1][i] = &As[1][(i * 32 + wv * 8) * 64];
  }

  // B staging map: thread covers k = tkq*4 .. tkq*4+3, n = tnb..tnb+3
  const int tkq = tid >> 4;          // 0..15 (8B k-chunk)
  const int tnb = (tid & 15) * 4;    // 0..60
  const float* bsrc = w2 + (size_t)e * (2048 * 1024) + (size_t)(tkq * 4) * 1024 + n0 + tnb;

  const int wm = wv & 1, wn = wv >> 1;
  const int fr = lane & 15, q = lane >> 4;

  f32x4 acc[4][2];
  #pragma unroll
  for (int a = 0; a < 4; ++a)
    #pragma unroll
    for (int b = 0; b < 2; ++b) acc[a][b] = (f32x4){0.f, 0.f, 0.f, 0.f};

  auto loadB = [&](float4* fv){
    #pragma unroll
    for (int j = 0; j < 4; ++j) fv[j] = *(const float4*)(bsrc + (size_t)j * 1024);
    bsrc += (size_t)64 * 1024;
  };
  auto writeB = [&](u16* B, const float4* fv){
    #pragma unroll
    for (int c = 0; c < 4; ++c){
      const int nr = tnb + c;
      u16x4 wd;
      wd[0] = f2bfh(getc(fv[0], c)); wd[1] = f2bfh(getc(fv[1], c));
      wd[2] = f2bfh(getc(fv[2], c)); wd[3] = f2bfh(getc(fv[3], c));
      *(u16x4*)((char*)B + nr * 128 + (((tkq >> 1) ^ ((nr >> 1) & 7)) << 4) + ((tkq & 1) << 3)) = wd;
    }
  };
  auto compute = [&](const u16* A, const u16* B){
    #pragma unroll
    for (int hh = 0; hh < 2; ++hh){
      const int puA = (((hh * 4) + q) ^ (fr & 7)) * 8;
      const int puB = (((hh * 4) + q) ^ ((fr >> 1) & 7)) * 8;
      bf16x8 af[4], bq[2];
      #pragma unroll
      for (int fm = 0; fm < 4; ++fm) af[fm] = *(const bf16x8*)&A[(wm * 64 + fm * 16 + fr) * 64 + puA];
      #pragma unroll
      for (int fn = 0; fn < 2; ++fn) bq[fn] = *(const bf16x8*)&B[(wn * 32 + fn * 16 + fr) * 64 + puB];
      #pragma unroll
      for (int fm = 0; fm < 4; ++fm)
        #pragma unroll
        for (int fn = 0; fn < 2; ++fn)
          acc[fm][fn] = __builtin_amdgcn_mfma_f32_16x16x32_bf16(af[fm], bq[fn], acc[fm][fn], 0, 0, 0);
    }
  };

  // prologue: stage tile 0
  {
    #pragma unroll
    for (int i = 0; i < 4; ++i){ gload16(asrc[i], adst[0][i]); asrc[i] += 64; }
    float4 fv[4];
    loadB(fv);
    writeB(Bs[0], fv);
  }
  __syncthreads();

  int cur = 0;
  for (int tt = 0; tt < 31; ++tt){
    const int nxt = cur ^ 1;
    #pragma unroll
    for (int i = 0; i < 4; ++i){ gload16(asrc[i], adst[nxt][i]); asrc[i] += 64; }
    float4 fv[4];
    loadB(fv);
    compute(As[cur], Bs[cur]);
    writeB(Bs[nxt], fv);
    __syncthreads();
    cur = nxt;
  }
  compute(As[cur], Bs[cur]);

  const int cb = n0 + wn * 32 + fr;
  float b2v[2];
  #pragma unroll
  for (int fn = 0; fn < 2; ++fn) b2v[fn] = b2[e * 1024 + cb + fn * 16];
  const int rq = q * 4;
  #pragma unroll
  for (int fm = 0; fm < 4; ++fm)
    #pragma unroll
    for (int rr = 0; rr < 4; ++rr){
      const int row = m0 + wm * 64 + fm * 16 + rq + rr;
      if (row < count){
        const float wt = wt_of[off + row];
        #pragma unroll
        for (int fn = 0; fn < 2; ++fn){
          const float v = (acc[fm][fn][rr] + b2v[fn]) * wt;
          ys[(size_t)(off + row) * 1024 + cb + fn * 16] = f2bf(v);
        }
      }
    }
}

// ---------------- final: out = x + ys[slot0] + ys[slot1], fp32 out ----------------
__global__ __launch_bounds__(256) void k_final(
    const float* __restrict__ x, const u16* __restrict__ ys,
    const int* __restrict__ slot_of, float* __restrict__ out)
{
  const int gid = blockIdx.x * 256 + threadIdx.x;
  const int token = gid >> 8;
  const int c0 = (gid & 255) * 4;
  const int s0 = slot_of[token * 2], s1 = slot_of[token * 2 + 1];
  const float4 xv = *(const float4*)&x[(size_t)token * 1024 + c0];
  const u16x4 y0 = *(const u16x4*)&ys[(size_t)s0 * 1024 + c0];
  const u16x4 y1 = *(const u16x4*)&ys[(size_t)s1 * 1024 + c0];
  float4 o;
  o.x = xv.x + bf2f(y0[0]) + bf2f(y1[0]);
  o.y = xv.y + bf2f(y0[1]) + bf2f(y1[1]);
  o.z = xv.z + bf2f(y0[2]) + bf2f(y1[2]);
  o.w = xv.w + bf2f(y0[3]) + bf2f(y1[3]);
  *(float4*)&out[(size_t)token * 1024 + c0] = o;
}

extern "C" void kernel_launch(void* const* d_in, const int* in_sizes, int n_in,
                              void* d_out, int out_size, void* d_ws, size_t ws_size,
                              hipStream_t stream)
{
  const float* x   = (const float*)d_in[0];
  const float* nsc = (const float*)d_in[1];
  const float* gw  = (const float*)d_in[2];
  const float* gb  = (const float*)d_in[3];
  const float* w1  = (const float*)d_in[4];
  const float* b1  = (const float*)d_in[5];
  const float* w2  = (const float*)d_in[6];
  const float* b2  = (const float*)d_in[7];
  float* out = (float*)d_out;
  char* ws = (char*)d_ws;

  size_t o = 0;
  auto alloc = [&](size_t bytes){ size_t r = o; o = (o + bytes + 255) & ~(size_t)255; return r; };
  const size_t o_t    = alloc((size_t)2048 * 1024 * 2);        // t bf16
  const size_t o_h    = alloc((size_t)4096 * 2048 * 2);        // swiglu output bf16
  const size_t o_ys   = alloc((size_t)4096 * 1024 * 2);        // per-slot expert output bf16
  const size_t o_topi = alloc(4096 * 4);
  const size_t o_topp = alloc(4096 * 4);
  const size_t o_posg = alloc(4096 * 4);
  const size_t o_tok  = alloc(4096 * 4);
  const size_t o_wt   = alloc(4096 * 4);
  const size_t o_slot = alloc(4096 * 4);
  const size_t o_cnt  = alloc(8 * 4);
  const size_t o_offs = alloc(8 * 4);
  if (ws_size < o) return;  // ws too small -> output stays zero (diagnostic: absmax == 5.28125)

  u16*   t_ws  = (u16*)(ws + o_t);
  u16*   h_ws  = (u16*)(ws + o_h);
  u16*   ys    = (u16*)(ws + o_ys);
  int*   topi  = (int*)(ws + o_topi);
  float* topp  = (float*)(ws + o_topp);
  int*   posg  = (int*)(ws + o_posg);
  int*   tok   = (int*)(ws + o_tok);
  float* wt    = (float*)(ws + o_wt);
  int*   slot  = (int*)(ws + o_slot);
  int*   cnt   = (int*)(ws + o_cnt);
  int*   offs  = (int*)(ws + o_offs);

  k_rms  <<<2048, 256, 0, stream>>>(x, nsc, gw, gb, t_ws, topi, topp);
  k_route<<<1, 256, 0, stream>>>(topi, topp, cnt, offs, tok, wt, slot, posg);
  k_gemm1<<<dim3(32, 16, 8), 256, 0, stream>>>(t_ws, w1, b1, cnt, offs, tok, h_ws);
  k_gemm2<<<dim3(16, 16, 8), 256, 0, stream>>>(h_ws, w2, b2, cnt, offs, wt, ys);
  k_final<<<2048, 256, 0, stream>>>(x, ys, slot, out);
}